// Round 21
// baseline (267.435 us; speedup 1.0000x reference)
//
#include <hip/hip_runtime.h>
#include <hip/hip_bf16.h>

#define THREADS 256
#define NBLKA 256          // pass-A blocks per graph
#define CAPB 3072          // pass-B LDS edge capacity (mean bucket = 819)
#define NG 2048            // gather grid

typedef __attribute__((ext_vector_type(8))) short s16x8;   // 8 bf16 = 4 VGPR
typedef __attribute__((ext_vector_type(4))) float f32x4;

// bf16 helpers (RNE)
static __device__ __forceinline__ unsigned short f2bf(float f) {
  union { float f; unsigned u; } v; v.f = f;
  unsigned r = (v.u + 0x7FFF + ((v.u >> 16) & 1)) >> 16;
  return (unsigned short)r;
}
static __device__ __forceinline__ float bf2f(unsigned short h) {
  union { unsigned u; float f; } v; v.u = ((unsigned)h) << 16;
  return v.f;
}

// ---------- CSR build: two-level counting sort ----------
__global__ void k_histA(const int* __restrict__ col_s, const int* __restrict__ col_f,
                        int* __restrict__ hm_s, int* __restrict__ hm_f, int E, int nbk) {
  const int* col = blockIdx.y ? col_f : col_s;
  int*       hm  = blockIdx.y ? hm_f  : hm_s;
  __shared__ int h[1024];
  for (int i = threadIdx.x; i < nbk; i += THREADS) h[i] = 0;
  __syncthreads();
  for (int e = blockIdx.x * THREADS + threadIdx.x; e < E; e += THREADS * NBLKA)
    atomicAdd(&h[col[e] >> 6], 1);
  __syncthreads();
  for (int b = threadIdx.x; b < nbk; b += THREADS) hm[b * NBLKA + blockIdx.x] = h[b];
}

__global__ void k_scanA1(const int* __restrict__ hm_s, const int* __restrict__ hm_f,
                         int* __restrict__ sc_s, int* __restrict__ sc_f,
                         int* __restrict__ bsum, int M, int nbk) {
  const int* hm = blockIdx.y ? hm_f : hm_s;
  int*       sc = blockIdx.y ? sc_f : sc_s;
  __shared__ int buf[THREADS];
  int idx = blockIdx.x * THREADS + threadIdx.x;
  int v = (idx < M) ? hm[idx] : 0;
  buf[threadIdx.x] = v;
  __syncthreads();
  #pragma unroll
  for (int off = 1; off < THREADS; off <<= 1) {
    int t = (threadIdx.x >= off) ? buf[threadIdx.x - off] : 0;
    __syncthreads();
    buf[threadIdx.x] += t;
    __syncthreads();
  }
  if (idx < M) sc[idx] = buf[threadIdx.x] - v;
  if (threadIdx.x == THREADS - 1) bsum[blockIdx.y * nbk + blockIdx.x] = buf[THREADS - 1];
}

__global__ void k_scanA2(int* __restrict__ bsum, int nb) {
  int* b = bsum + blockIdx.x * nb;
  __shared__ int buf[THREADS];
  __shared__ int carry;
  if (threadIdx.x == 0) carry = 0;
  __syncthreads();
  for (int base = 0; base < nb; base += THREADS) {
    int i = base + threadIdx.x;
    int v = (i < nb) ? b[i] : 0;
    buf[threadIdx.x] = v;
    __syncthreads();
    #pragma unroll
    for (int off = 1; off < THREADS; off <<= 1) {
      int t = (threadIdx.x >= off) ? buf[threadIdx.x - off] : 0;
      __syncthreads();
      buf[threadIdx.x] += t;
      __syncthreads();
    }
    if (i < nb) b[i] = carry + buf[threadIdx.x] - v;
    __syncthreads();
    if (threadIdx.x == 0) carry += buf[THREADS - 1];
    __syncthreads();
  }
}

// tmp record: dest(16) | src(16) | bf16(w)(16) in a u64.  (bsum folded at read)
__global__ void k_scatA(const int* __restrict__ ei_s, const float* __restrict__ w_s,
                        const int* __restrict__ ei_f, const float* __restrict__ w_f,
                        const int* __restrict__ sc_s, const int* __restrict__ sc_f,
                        const int* __restrict__ bsum,
                        unsigned long long* __restrict__ tmp_s,
                        unsigned long long* __restrict__ tmp_f, int E, int nbk) {
  const int*          ei  = blockIdx.y ? ei_f  : ei_s;
  const float*        w   = blockIdx.y ? w_f   : w_s;
  const int*          sc  = blockIdx.y ? sc_f  : sc_s;
  unsigned long long* tmp = blockIdx.y ? tmp_f : tmp_s;
  const int* bs = bsum + blockIdx.y * nbk;
  __shared__ int bas[1024];
  __shared__ int h2[1024];
  for (int b = threadIdx.x; b < nbk; b += THREADS) {
    bas[b] = sc[b * NBLKA + blockIdx.x] + bs[b];
    h2[b] = 0;
  }
  __syncthreads();
  for (int e = blockIdx.x * THREADS + threadIdx.x; e < E; e += THREADS * NBLKA) {
    int c = ei[E + e], r = ei[e];
    int b = c >> 6;
    int rk = atomicAdd(&h2[b], 1);
    tmp[bas[b] + rk] = ((unsigned long long)(unsigned)(c & 0xFFFF) << 32)
                     | ((unsigned long long)(unsigned)(r & 0xFFFF) << 16)
                     | (unsigned long long)f2bf(w[e]);
  }
}

// Level B: per-bucket counting sort in LDS; dis = rsqrt(1+Σw); edge weight
// pre-scaled by dis[dest]. final ed record: src(16) | bf16(w*dis_dest)(16).
__global__ __launch_bounds__(THREADS) void k_passB(
    const unsigned long long* __restrict__ tmp_s, const unsigned long long* __restrict__ tmp_f,
    const int* __restrict__ sc_s, const int* __restrict__ sc_f,
    const int* __restrict__ bsum,
    unsigned* __restrict__ ed_s, unsigned* __restrict__ ed_f,
    int* __restrict__ rp_s, int* __restrict__ rp_f,
    float* __restrict__ dis_s, float* __restrict__ dis_f, int E, int N, int nbk) {
  const unsigned long long* tmp = blockIdx.y ? tmp_f : tmp_s;
  const int*                sc  = blockIdx.y ? sc_f  : sc_s;
  unsigned*                 ed  = blockIdx.y ? ed_f  : ed_s;
  int*                      rp  = blockIdx.y ? rp_f  : rp_s;
  float*                    dis = blockIdx.y ? dis_f : dis_s;
  const int* bs = bsum + blockIdx.y * nbk;
  int b = blockIdx.x;
  int base = sc[b * NBLKA] + bs[b];
  int next = (b + 1 < nbk) ? sc[(b + 1) * NBLKA] + bs[b + 1] : E;
  int cnt = next - base;
  __shared__ unsigned long long eb[CAPB];
  __shared__ unsigned outb[CAPB];
  __shared__ int h[64], exc[65], h2[64];
  int tid = threadIdx.x;
  if (tid < 64) { h[tid] = 0; h2[tid] = 0; }
  __syncthreads();
  if (cnt <= CAPB) {
    for (int i = tid; i < cnt; i += THREADS) {
      unsigned long long rec = tmp[base + i];
      eb[i] = rec;
      atomicAdd(&h[(int)((rec >> 32) & 63)], 1);
    }
    __syncthreads();
    if (tid == 0) { int a = 0; for (int i = 0; i < 64; ++i) { exc[i] = a; a += h[i]; } exc[64] = a; }
    __syncthreads();
    for (int i = tid; i < cnt; i += THREADS) {
      unsigned long long rec = eb[i];
      int ld = (int)((rec >> 32) & 63);
      int rk = atomicAdd(&h2[ld], 1);
      outb[exc[ld] + rk] = (unsigned)((rec >> 16) & 0xFFFF) | ((unsigned)(rec & 0xFFFF) << 16);
    }
    __syncthreads();
    if (tid < 64) {
      int v = b * 64 + tid;
      if (v < N) {
        float s = 0.f;
        for (int j = exc[tid]; j < exc[tid + 1]; ++j) s += bf2f((unsigned short)(outb[j] >> 16));
        float d = rsqrtf(1.0f + s);
        dis[v] = d;
        rp[v] = base + exc[tid];
        for (int j = exc[tid]; j < exc[tid + 1]; ++j) {   // fold dis[dest] into weight
          unsigned rec = outb[j];
          outb[j] = (rec & 0xFFFF) |
                    ((unsigned)f2bf(bf2f((unsigned short)(rec >> 16)) * d) << 16);
        }
      }
    }
    __syncthreads();
    for (int i = tid; i < cnt; i += THREADS) ed[base + i] = outb[i];
  } else {   // fallback (statistically unreachable)
    for (int i = tid; i < cnt; i += THREADS) atomicAdd(&h[(int)((tmp[base + i] >> 32) & 63)], 1);
    __syncthreads();
    if (tid == 0) { int a = 0; for (int i = 0; i < 64; ++i) { exc[i] = a; a += h[i]; } exc[64] = a; }
    __syncthreads();
    for (int i = tid; i < cnt; i += THREADS) {
      unsigned long long rec = tmp[base + i];
      int ld = (int)((rec >> 32) & 63);
      int rk = atomicAdd(&h2[ld], 1);
      ed[base + exc[ld] + rk] = (unsigned)((rec >> 16) & 0xFFFF) | ((unsigned)(rec & 0xFFFF) << 16);
    }
    __syncthreads();
    if (tid < 64) {
      int v = b * 64 + tid;
      if (v < N) {
        float s = 0.f;
        for (int j = exc[tid]; j < exc[tid + 1]; ++j) s += bf2f((unsigned short)(ed[base + j] >> 16));
        float d = rsqrtf(1.0f + s);
        dis[v] = d;
        rp[v] = base + exc[tid];
        for (int j = exc[tid]; j < exc[tid + 1]; ++j) {
          unsigned rec = ed[base + j];
          ed[base + j] = (rec & 0xFFFF) |
                         ((unsigned)f2bf(bf2f((unsigned short)(rec >> 16)) * d) << 16);
        }
      }
    }
  }
  if (b == 0 && tid == 0) rp[N] = E;
}

// ---------- one-time weight prep: f32 [k][n] -> bf16 transposed [n][k], XOR-swizzled ----------
__global__ void k_prew(const float* __restrict__ W_s, const float* __restrict__ W_f,
                       unsigned* __restrict__ Wsw) {
  int m = blockIdx.x;                 // 0..2L-1: matrix id (l = m>>1, branch = m&1)
  const float* W = ((m & 1) ? W_f : W_s) + (size_t)(m >> 1) * 128 * 128;
  unsigned* dst = Wsw + (size_t)m * 8192;
  int tid = threadIdx.x;
  #pragma unroll
  for (int p = 0; p < 32; ++p) {
    int idx = p * 256 + tid;          // dword index
    int kp = idx & 63, n = idx >> 6;  // k = 2*kp
    float w0 = W[(2 * kp) * 128 + n];
    float w1 = W[(2 * kp + 1) * 128 + n];
    unsigned pk = (unsigned)f2bf(w0) | ((unsigned)f2bf(w1) << 16);
    unsigned byte = (unsigned)(n * 256 + kp * 4) ^ ((unsigned)(n & 7) << 4);
    *(unsigned*)((char*)dst + byte) = pk;
  }
}

// ---------- MFMA GEMM with fused BN+ReLU+cast on the A path ----------
// mode 0: A = x (f32), pack to bf16. mode 1: A = agg (bf16); apply per-col
// scale/shift (stats,gamma,beta of the PREVIOUS layer) + ReLU, repack.
// C(bf16) = dis[row] * (A' @ W).
__global__ __launch_bounds__(THREADS) void k_gemm_mfma(
    const void* __restrict__ Araw,
    const unsigned* __restrict__ Wsw,
    const float* __restrict__ dis_s, const float* __restrict__ dis_f,
    const double* __restrict__ stats, const float* __restrict__ gamma,
    const float* __restrict__ beta,
    unsigned short* __restrict__ C0, unsigned short* __restrict__ C1,
    int N, int mode) {
  const unsigned* Wm  = Wsw + (size_t)blockIdx.y * 8192;
  const float*    dis = blockIdx.y ? dis_f : dis_s;
  unsigned short* C   = blockIdx.y ? C1 : C0;
  const float*          Af = (const float*)Araw;
  const unsigned short* Ab = (const unsigned short*)Araw;
  __shared__ unsigned Wt[8192];                  // 32 KiB
  __shared__ float scl[128], shf[128];
  int tid = threadIdx.x;
  #pragma unroll
  for (int i = 0; i < 8; ++i)
    ((float4*)Wt)[i * 256 + tid] = ((const float4*)Wm)[i * 256 + tid];
  if (mode && tid < 128) {
    double invN = 1.0 / (double)N;
    double m   = stats[tid] * invN;
    double var = stats[128 + tid] * invN - m * m;
    float s = gamma[tid] * rsqrtf((float)var + 1e-5f);
    scl[tid] = s;
    shf[tid] = beta[tid] - (float)m * s;
  }
  __syncthreads();

  int wid = tid >> 6, lane = tid & 63;
  int kg = lane >> 4;                            // 0..3
  int rbase = blockIdx.x * 128 + wid * 32;
  int rown[2];
  #pragma unroll
  for (int rt = 0; rt < 2; ++rt) {
    int r = rbase + rt * 16 + (lane & 15); if (r > N - 1) r = N - 1;   // clamp; store guarded
    rown[rt] = r;
  }

  f32x4 acc[2][8];
  #pragma unroll
  for (int rt = 0; rt < 2; ++rt)
    #pragma unroll
    for (int nt = 0; nt < 8; ++nt) acc[rt][nt] = (f32x4){0.f, 0.f, 0.f, 0.f};

  #pragma unroll
  for (int ks = 0; ks < 4; ++ks) {
    int kbase = ks * 32 + kg * 8;
    s16x8 af[2];
    #pragma unroll
    for (int rt = 0; rt < 2; ++rt) {
      float a[8];
      if (mode) {
        s16x8 raw = *(const s16x8*)(Ab + (size_t)rown[rt] * 128 + kbase);
        #pragma unroll
        for (int j = 0; j < 8; ++j) {
          float vv = bf2f((unsigned short)raw[j]);
          vv = fmaf(vv, scl[kbase + j], shf[kbase + j]);
          a[j] = vv > 0.f ? vv : 0.f;
        }
      } else {
        float4 a0 = *(const float4*)(Af + (size_t)rown[rt] * 128 + kbase);
        float4 a1 = *(const float4*)(Af + (size_t)rown[rt] * 128 + kbase + 4);
        a[0] = a0.x; a[1] = a0.y; a[2] = a0.z; a[3] = a0.w;
        a[4] = a1.x; a[5] = a1.y; a[6] = a1.z; a[7] = a1.w;
      }
      s16x8 f;
      #pragma unroll
      for (int j = 0; j < 8; ++j) f[j] = (short)f2bf(a[j]);
      af[rt] = f;
    }
    #pragma unroll
    for (int nt = 0; nt < 8; ++nt) {
      int col = nt * 16 + (lane & 15);
      unsigned byte = (unsigned)(col * 256 + kbase * 2) ^ ((unsigned)(col & 7) << 4);
      s16x8 bfrag = *(const s16x8*)((char*)Wt + byte);
      acc[0][nt] = __builtin_amdgcn_mfma_f32_16x16x32_bf16(af[0], bfrag, acc[0][nt], 0, 0, 0);
      acc[1][nt] = __builtin_amdgcn_mfma_f32_16x16x32_bf16(af[1], bfrag, acc[1][nt], 0, 0, 0);
    }
  }
  // C/D layout (m89): col = lane&15, row = (lane>>4)*4 + reg. Scale row by dis[row].
  #pragma unroll
  for (int rt = 0; rt < 2; ++rt) {
    #pragma unroll
    for (int r = 0; r < 4; ++r) {
      int row = rbase + rt * 16 + kg * 4 + r;
      if (row < N) {
        float d = dis[row];
        #pragma unroll
        for (int nt = 0; nt < 8; ++nt) {
          int col = nt * 16 + (lane & 15);
          C[(size_t)row * 128 + col] = f2bf(acc[rt][nt][r] * d);
        }
      }
    }
  }
}

// ---------- aggregation: paired vertices (v, v+1), 4+4 interleaved batches ----------
// agg(bf16)[v] = dvs*t's[v] + dvf*t'f[v] + Σ_s w''·t's[src] + Σ_f w''·t'f[src]
__global__ __launch_bounds__(THREADS) void k_gather(
    const unsigned short* __restrict__ t_sc, const unsigned short* __restrict__ t_fc,
    const int* __restrict__ rp_s, const unsigned* __restrict__ ed_s,
    const int* __restrict__ rp_f, const unsigned* __restrict__ ed_f,
    const float* __restrict__ dis_s, const float* __restrict__ dis_f,
    unsigned short* __restrict__ aggb, float* __restrict__ pb, int N) {
  __shared__ float redS[4][128], redQ[4][128];
  int tid    = threadIdx.x;
  int wid    = tid >> 6;
  int lane   = tid & 63;
  int gw     = (blockIdx.x * blockDim.x + tid) >> 6;
  int nwaves = (gridDim.x * blockDim.x) >> 6;
  float s0 = 0.f, s1 = 0.f, q0 = 0.f, q1 = 0.f;
  for (int v0 = gw * 2; v0 < N; v0 += 2 * nwaves) {
    int v1 = v0 + 1;                       // N even -> v1 < N
    float dvsA = dis_s[v0], dvfA = dis_f[v0];
    float dvsB = dis_s[v1], dvfB = dis_f[v1];
    unsigned aA = ((const unsigned*)(t_sc + (size_t)v0 * 128))[lane];
    unsigned bA = ((const unsigned*)(t_fc + (size_t)v0 * 128))[lane];
    unsigned aB = ((const unsigned*)(t_sc + (size_t)v1 * 128))[lane];
    unsigned bB = ((const unsigned*)(t_fc + (size_t)v1 * 128))[lane];
    float axA = bf2f((unsigned short)aA) * dvsA + bf2f((unsigned short)bA) * dvfA;
    float ayA = bf2f((unsigned short)(aA >> 16)) * dvsA + bf2f((unsigned short)(bA >> 16)) * dvfA;
    float axB = bf2f((unsigned short)aB) * dvsB + bf2f((unsigned short)bB) * dvfB;
    float ayB = bf2f((unsigned short)(aB >> 16)) * dvsB + bf2f((unsigned short)(bB >> 16)) * dvfB;

    #pragma unroll 1
    for (int g = 0; g < 2; ++g) {
      const int*            rp = g ? rp_f : rp_s;
      const unsigned*       ed = g ? ed_f : ed_s;
      const unsigned short* t  = g ? t_fc : t_sc;
      int eA = rp[v0], mA = rp[v0 + 1];
      int eB = mA,     mB = rp[v0 + 2];
      // joint 4+4 batches: 8 independent loads in flight
      while (eA + 3 < mA && eB + 3 < mB) {
        unsigned q[8];
        #pragma unroll
        for (int j = 0; j < 4; ++j) q[j] = ed[eA + j];
        #pragma unroll
        for (int j = 0; j < 4; ++j) q[4 + j] = ed[eB + j];
        unsigned r[8];
        #pragma unroll
        for (int j = 0; j < 8; ++j)
          r[j] = ((const unsigned*)(t + (size_t)(q[j] & 0xFFFF) * 128))[lane];
        #pragma unroll
        for (int j = 0; j < 4; ++j) {
          float w = bf2f((unsigned short)(q[j] >> 16));
          axA = fmaf(bf2f((unsigned short)r[j]), w, axA);
          ayA = fmaf(bf2f((unsigned short)(r[j] >> 16)), w, ayA);
        }
        #pragma unroll
        for (int j = 4; j < 8; ++j) {
          float w = bf2f((unsigned short)(q[j] >> 16));
          axB = fmaf(bf2f((unsigned short)r[j]), w, axB);
          ayB = fmaf(bf2f((unsigned short)(r[j] >> 16)), w, ayB);
        }
        eA += 4; eB += 4;
      }
      // drain A
      for (; eA + 3 < mA; eA += 4) {
        unsigned q[4];
        #pragma unroll
        for (int j = 0; j < 4; ++j) q[j] = ed[eA + j];
        unsigned r[4];
        #pragma unroll
        for (int j = 0; j < 4; ++j)
          r[j] = ((const unsigned*)(t + (size_t)(q[j] & 0xFFFF) * 128))[lane];
        #pragma unroll
        for (int j = 0; j < 4; ++j) {
          float w = bf2f((unsigned short)(q[j] >> 16));
          axA = fmaf(bf2f((unsigned short)r[j]), w, axA);
          ayA = fmaf(bf2f((unsigned short)(r[j] >> 16)), w, ayA);
        }
      }
      for (; eA < mA; ++eA) {
        unsigned qa = ed[eA];
        unsigned ra = ((const unsigned*)(t + (size_t)(qa & 0xFFFF) * 128))[lane];
        float w = bf2f((unsigned short)(qa >> 16));
        axA = fmaf(bf2f((unsigned short)ra), w, axA);
        ayA = fmaf(bf2f((unsigned short)(ra >> 16)), w, ayA);
      }
      // drain B
      for (; eB + 3 < mB; eB += 4) {
        unsigned q[4];
        #pragma unroll
        for (int j = 0; j < 4; ++j) q[j] = ed[eB + j];
        unsigned r[4];
        #pragma unroll
        for (int j = 0; j < 4; ++j)
          r[j] = ((const unsigned*)(t + (size_t)(q[j] & 0xFFFF) * 128))[lane];
        #pragma unroll
        for (int j = 0; j < 4; ++j) {
          float w = bf2f((unsigned short)(q[j] >> 16));
          axB = fmaf(bf2f((unsigned short)r[j]), w, axB);
          ayB = fmaf(bf2f((unsigned short)(r[j] >> 16)), w, ayB);
        }
      }
      for (; eB < mB; ++eB) {
        unsigned qa = ed[eB];
        unsigned ra = ((const unsigned*)(t + (size_t)(qa & 0xFFFF) * 128))[lane];
        float w = bf2f((unsigned short)(qa >> 16));
        axB = fmaf(bf2f((unsigned short)ra), w, axB);
        ayB = fmaf(bf2f((unsigned short)(ra >> 16)), w, ayB);
      }
    }
    ((unsigned*)(aggb + (size_t)v0 * 128))[lane] =
        (unsigned)f2bf(axA) | ((unsigned)f2bf(ayA) << 16);
    ((unsigned*)(aggb + (size_t)v1 * 128))[lane] =
        (unsigned)f2bf(axB) | ((unsigned)f2bf(ayB) << 16);
    s0 += axA + axB; s1 += ayA + ayB;
    q0 = fmaf(axA, axA, q0); q0 = fmaf(axB, axB, q0);
    q1 = fmaf(ayA, ayA, q1); q1 = fmaf(ayB, ayB, q1);
  }
  // block-level stats partials (deterministic; no atomics)
  redS[wid][lane * 2] = s0; redS[wid][lane * 2 + 1] = s1;
  redQ[wid][lane * 2] = q0; redQ[wid][lane * 2 + 1] = q1;
  __syncthreads();
  if (tid < 128) {
    pb[(size_t)blockIdx.x * 256 + tid] =
        redS[0][tid] + redS[1][tid] + redS[2][tid] + redS[3][tid];
  } else {
    int c = tid - 128;
    pb[(size_t)blockIdx.x * 256 + tid] =
        redQ[0][c] + redQ[1][c] + redQ[2][c] + redQ[3][c];
  }
}

// ---------- hierarchical deterministic stats reduce: NG x 256 -> 64 x 256 -> 256 ----------
__global__ void k_stats2a(const float* __restrict__ pb, double* __restrict__ pb2) {
  int b = blockIdx.x, t = threadIdx.x;
  double s = 0;
  for (int r = 0; r < NG / 64; ++r)
    s += (double)pb[(size_t)(b * (NG / 64) + r) * 256 + t];
  pb2[(size_t)b * 256 + t] = s;
}

__global__ void k_stats2b(const double* __restrict__ pb2, double* __restrict__ stats) {
  int t = threadIdx.x;
  double s = 0;
  for (int b = 0; b < 64; ++b) s += pb2[(size_t)b * 256 + t];
  stats[t] = s;
}

// ---------- final-layer BN+ReLU: agg bf16 -> f32 out ----------
__global__ void k_bn(const unsigned short* __restrict__ aggb, const double* __restrict__ stats,
                     const float* __restrict__ gamma, const float* __restrict__ beta,
                     float* __restrict__ outf, int N) {
  int total2 = N * 64;   // dwords (2 cols each)
  double invN = 1.0 / (double)N;
  for (int i = blockIdx.x * blockDim.x + threadIdx.x; i < total2; i += gridDim.x * blockDim.x) {
    int c = (i & 63) * 2;
    unsigned pk = ((const unsigned*)aggb)[i];
    double m0   = stats[c] * invN;
    double var0 = stats[128 + c] * invN - m0 * m0;
    float sc0 = gamma[c] * rsqrtf((float)var0 + 1e-5f);
    float sh0 = beta[c] - (float)m0 * sc0;
    double m1   = stats[c + 1] * invN;
    double var1 = stats[128 + c + 1] * invN - m1 * m1;
    float sc1 = gamma[c + 1] * rsqrtf((float)var1 + 1e-5f);
    float sh1 = beta[c + 1] - (float)m1 * sc1;
    float v0 = fmaf(bf2f((unsigned short)pk), sc0, sh0);
    float v1 = fmaf(bf2f((unsigned short)(pk >> 16)), sc1, sh1);
    ((float2*)outf)[i] = make_float2(v0 > 0.f ? v0 : 0.f, v1 > 0.f ? v1 : 0.f);
  }
}

extern "C" void kernel_launch(void* const* d_in, const int* in_sizes, int n_in,
                              void* d_out, int out_size, void* d_ws, size_t ws_size,
                              hipStream_t stream) {
  const float* x     = (const float*)d_in[0];
  const int*   ei_s  = (const int*)d_in[1];
  const float* w_s   = (const float*)d_in[2];
  const int*   ei_f  = (const int*)d_in[3];
  const float* w_f   = (const float*)d_in[4];
  const float* W_s   = (const float*)d_in[5];
  const float* W_f   = (const float*)d_in[7];
  const float* gamma = (const float*)d_in[9];
  const float* beta  = (const float*)d_in[10];
  float* out = (float*)d_out;

  const int N = in_sizes[0] / 128;
  const int E = in_sizes[2];
  const int L = in_sizes[5] / (128 * 128);
  const int nbk = (N + 63) >> 6;            // 782 coarse buckets (64 vertices each)
  const int M = nbk * NBLKA;                // count-matrix size per graph

  char* ws = (char*)d_ws;
  size_t off = 0;
  auto alloc = [&](size_t bytes) -> void* {
    void* p = (void*)(ws + off);
    off += (bytes + 255) & ~(size_t)255;
    return p;
  };
  double* stats = (double*)alloc(256 * sizeof(double));
  float*  pb    = (float*)alloc((size_t)NG * 256 * sizeof(float));
  double* pb2   = (double*)alloc((size_t)64 * 256 * sizeof(double));
  unsigned* Wsw = (unsigned*)alloc((size_t)2 * L * 8192 * 4);
  unsigned short* t_sc = (unsigned short*)alloc((size_t)N * 128 * 2);
  unsigned short* t_fc = (unsigned short*)alloc((size_t)N * 128 * 2);
  unsigned short* aggb = (unsigned short*)alloc((size_t)N * 128 * 2);
  float* dis_s = (float*)alloc((size_t)N * 4);
  float* dis_f = (float*)alloc((size_t)N * 4);
  int*   rp_s  = (int*)alloc((size_t)(N + 1) * 4);
  int*   rp_f  = (int*)alloc((size_t)(N + 1) * 4);
  int*   hm_s  = (int*)alloc((size_t)M * 4);
  int*   hm_f  = (int*)alloc((size_t)M * 4);
  int*   sc_s  = (int*)alloc((size_t)M * 4);
  int*   sc_f  = (int*)alloc((size_t)M * 4);
  unsigned long long* tmp_s = (unsigned long long*)alloc((size_t)E * 8);
  unsigned long long* tmp_f = (unsigned long long*)alloc((size_t)E * 8);
  unsigned* ed_s = (unsigned*)alloc((size_t)E * 4);
  unsigned* ed_f = (unsigned*)alloc((size_t)E * 4);
  int* bsum = (int*)alloc((size_t)2 * nbk * 4);

  dim3 ga(NBLKA, 2), gm(nbk, 2);

  // one-time weight prep + CSR/degree build (layer-invariant)
  k_prew<<<2 * L, THREADS, 0, stream>>>(W_s, W_f, Wsw);
  k_histA<<<ga, THREADS, 0, stream>>>(ei_s + E, ei_f + E, hm_s, hm_f, E, nbk);
  k_scanA1<<<gm, THREADS, 0, stream>>>(hm_s, hm_f, sc_s, sc_f, bsum, M, nbk);
  k_scanA2<<<2, THREADS, 0, stream>>>(bsum, nbk);
  k_scatA<<<ga, THREADS, 0, stream>>>(ei_s, w_s, ei_f, w_f, sc_s, sc_f, bsum,
                                      tmp_s, tmp_f, E, nbk);
  k_passB<<<gm, THREADS, 0, stream>>>(tmp_s, tmp_f, sc_s, sc_f, bsum, ed_s, ed_f,
                                      rp_s, rp_f, dis_s, dis_f, E, N, nbk);

  for (int l = 0; l < L; ++l) {
    dim3 gg((N + 127) / 128, 2);
    const void* Ain = (l == 0) ? (const void*)x : (const void*)aggb;
    const float* gm_prev = l ? gamma + (size_t)(l - 1) * 128 : gamma;
    const float* bt_prev = l ? beta  + (size_t)(l - 1) * 128 : beta;
    k_gemm_mfma<<<gg, THREADS, 0, stream>>>(Ain, Wsw + (size_t)l * 2 * 8192,
                                            dis_s, dis_f, stats, gm_prev, bt_prev,
                                            t_sc, t_fc, N, l ? 1 : 0);
    k_gather<<<NG, THREADS, 0, stream>>>(t_sc, t_fc, rp_s, ed_s, rp_f, ed_f,
                                         dis_s, dis_f, aggb, pb, N);
    k_stats2a<<<64, 256, 0, stream>>>(pb, pb2);
    k_stats2b<<<1, 256, 0, stream>>>(pb2, stats);
  }
  k_bn<<<2048, THREADS, 0, stream>>>(aggb, stats, gamma + (size_t)(L - 1) * 128,
                                     beta + (size_t)(L - 1) * 128, out, N);
}

// Round 23
// 233.498 us; speedup vs baseline: 1.1453x; 1.1453x over previous
//
#include <hip/hip_runtime.h>
#include <hip/hip_bf16.h>

#define THREADS 256
#define NBLKA 256          // pass-A blocks per graph
#define CAPB 3072          // pass-B LDS edge capacity (mean bucket = 819)
#define NG 2048            // gather grid

typedef __attribute__((ext_vector_type(8))) short s16x8;   // 8 bf16 = 4 VGPR
typedef __attribute__((ext_vector_type(4))) float f32x4;

// bf16 helpers (RNE)
static __device__ __forceinline__ unsigned short f2bf(float f) {
  union { float f; unsigned u; } v; v.f = f;
  unsigned r = (v.u + 0x7FFF + ((v.u >> 16) & 1)) >> 16;
  return (unsigned short)r;
}
static __device__ __forceinline__ float bf2f(unsigned short h) {
  union { unsigned u; float f; } v; v.u = ((unsigned)h) << 16;
  return v.f;
}

// ---------- CSR build: two-level counting sort ----------
__global__ void k_histA(const int* __restrict__ col_s, const int* __restrict__ col_f,
                        int* __restrict__ hm_s, int* __restrict__ hm_f, int E, int nbk) {
  const int* col = blockIdx.y ? col_f : col_s;
  int*       hm  = blockIdx.y ? hm_f  : hm_s;
  __shared__ int h[1024];
  for (int i = threadIdx.x; i < nbk; i += THREADS) h[i] = 0;
  __syncthreads();
  for (int e = blockIdx.x * THREADS + threadIdx.x; e < E; e += THREADS * NBLKA)
    atomicAdd(&h[col[e] >> 6], 1);
  __syncthreads();
  for (int b = threadIdx.x; b < nbk; b += THREADS) hm[b * NBLKA + blockIdx.x] = h[b];
}

__global__ void k_scanA1(const int* __restrict__ hm_s, const int* __restrict__ hm_f,
                         int* __restrict__ sc_s, int* __restrict__ sc_f,
                         int* __restrict__ bsum, int M, int nbk) {
  const int* hm = blockIdx.y ? hm_f : hm_s;
  int*       sc = blockIdx.y ? sc_f : sc_s;
  __shared__ int buf[THREADS];
  int idx = blockIdx.x * THREADS + threadIdx.x;
  int v = (idx < M) ? hm[idx] : 0;
  buf[threadIdx.x] = v;
  __syncthreads();
  #pragma unroll
  for (int off = 1; off < THREADS; off <<= 1) {
    int t = (threadIdx.x >= off) ? buf[threadIdx.x - off] : 0;
    __syncthreads();
    buf[threadIdx.x] += t;
    __syncthreads();
  }
  if (idx < M) sc[idx] = buf[threadIdx.x] - v;
  if (threadIdx.x == THREADS - 1) bsum[blockIdx.y * nbk + blockIdx.x] = buf[THREADS - 1];
}

__global__ void k_scanA2(int* __restrict__ bsum, int nb) {
  int* b = bsum + blockIdx.x * nb;
  __shared__ int buf[THREADS];
  __shared__ int carry;
  if (threadIdx.x == 0) carry = 0;
  __syncthreads();
  for (int base = 0; base < nb; base += THREADS) {
    int i = base + threadIdx.x;
    int v = (i < nb) ? b[i] : 0;
    buf[threadIdx.x] = v;
    __syncthreads();
    #pragma unroll
    for (int off = 1; off < THREADS; off <<= 1) {
      int t = (threadIdx.x >= off) ? buf[threadIdx.x - off] : 0;
      __syncthreads();
      buf[threadIdx.x] += t;
      __syncthreads();
    }
    if (i < nb) b[i] = carry + buf[threadIdx.x] - v;
    __syncthreads();
    if (threadIdx.x == 0) carry += buf[THREADS - 1];
    __syncthreads();
  }
}

// tmp record: dest(16) | src(16) | bf16(w)(16) in a u64.  (bsum folded at read)
__global__ void k_scatA(const int* __restrict__ ei_s, const float* __restrict__ w_s,
                        const int* __restrict__ ei_f, const float* __restrict__ w_f,
                        const int* __restrict__ sc_s, const int* __restrict__ sc_f,
                        const int* __restrict__ bsum,
                        unsigned long long* __restrict__ tmp_s,
                        unsigned long long* __restrict__ tmp_f, int E, int nbk) {
  const int*          ei  = blockIdx.y ? ei_f  : ei_s;
  const float*        w   = blockIdx.y ? w_f   : w_s;
  const int*          sc  = blockIdx.y ? sc_f  : sc_s;
  unsigned long long* tmp = blockIdx.y ? tmp_f : tmp_s;
  const int* bs = bsum + blockIdx.y * nbk;
  __shared__ int bas[1024];
  __shared__ int h2[1024];
  for (int b = threadIdx.x; b < nbk; b += THREADS) {
    bas[b] = sc[b * NBLKA + blockIdx.x] + bs[b];
    h2[b] = 0;
  }
  __syncthreads();
  for (int e = blockIdx.x * THREADS + threadIdx.x; e < E; e += THREADS * NBLKA) {
    int c = ei[E + e], r = ei[e];
    int b = c >> 6;
    int rk = atomicAdd(&h2[b], 1);
    tmp[bas[b] + rk] = ((unsigned long long)(unsigned)(c & 0xFFFF) << 32)
                     | ((unsigned long long)(unsigned)(r & 0xFFFF) << 16)
                     | (unsigned long long)f2bf(w[e]);
  }
}

// Level B: per-bucket counting sort in LDS; dis = rsqrt(1+Σw); edge weight
// pre-scaled by dis[dest]. final ed record: src(16) | bf16(w*dis_dest)(16).
__global__ __launch_bounds__(THREADS) void k_passB(
    const unsigned long long* __restrict__ tmp_s, const unsigned long long* __restrict__ tmp_f,
    const int* __restrict__ sc_s, const int* __restrict__ sc_f,
    const int* __restrict__ bsum,
    unsigned* __restrict__ ed_s, unsigned* __restrict__ ed_f,
    int* __restrict__ rp_s, int* __restrict__ rp_f,
    float* __restrict__ dis_s, float* __restrict__ dis_f, int E, int N, int nbk) {
  const unsigned long long* tmp = blockIdx.y ? tmp_f : tmp_s;
  const int*                sc  = blockIdx.y ? sc_f  : sc_s;
  unsigned*                 ed  = blockIdx.y ? ed_f  : ed_s;
  int*                      rp  = blockIdx.y ? rp_f  : rp_s;
  float*                    dis = blockIdx.y ? dis_f : dis_s;
  const int* bs = bsum + blockIdx.y * nbk;
  int b = blockIdx.x;
  int base = sc[b * NBLKA] + bs[b];
  int next = (b + 1 < nbk) ? sc[(b + 1) * NBLKA] + bs[b + 1] : E;
  int cnt = next - base;
  __shared__ unsigned long long eb[CAPB];
  __shared__ unsigned outb[CAPB];
  __shared__ int h[64], exc[65], h2[64];
  int tid = threadIdx.x;
  if (tid < 64) { h[tid] = 0; h2[tid] = 0; }
  __syncthreads();
  if (cnt <= CAPB) {
    for (int i = tid; i < cnt; i += THREADS) {
      unsigned long long rec = tmp[base + i];
      eb[i] = rec;
      atomicAdd(&h[(int)((rec >> 32) & 63)], 1);
    }
    __syncthreads();
    if (tid == 0) { int a = 0; for (int i = 0; i < 64; ++i) { exc[i] = a; a += h[i]; } exc[64] = a; }
    __syncthreads();
    for (int i = tid; i < cnt; i += THREADS) {
      unsigned long long rec = eb[i];
      int ld = (int)((rec >> 32) & 63);
      int rk = atomicAdd(&h2[ld], 1);
      outb[exc[ld] + rk] = (unsigned)((rec >> 16) & 0xFFFF) | ((unsigned)(rec & 0xFFFF) << 16);
    }
    __syncthreads();
    if (tid < 64) {
      int v = b * 64 + tid;
      if (v < N) {
        float s = 0.f;
        for (int j = exc[tid]; j < exc[tid + 1]; ++j) s += bf2f((unsigned short)(outb[j] >> 16));
        float d = rsqrtf(1.0f + s);
        dis[v] = d;
        rp[v] = base + exc[tid];
        for (int j = exc[tid]; j < exc[tid + 1]; ++j) {   // fold dis[dest] into weight
          unsigned rec = outb[j];
          outb[j] = (rec & 0xFFFF) |
                    ((unsigned)f2bf(bf2f((unsigned short)(rec >> 16)) * d) << 16);
        }
      }
    }
    __syncthreads();
    for (int i = tid; i < cnt; i += THREADS) ed[base + i] = outb[i];
  } else {   // fallback (statistically unreachable)
    for (int i = tid; i < cnt; i += THREADS) atomicAdd(&h[(int)((tmp[base + i] >> 32) & 63)], 1);
    __syncthreads();
    if (tid == 0) { int a = 0; for (int i = 0; i < 64; ++i) { exc[i] = a; a += h[i]; } exc[64] = a; }
    __syncthreads();
    for (int i = tid; i < cnt; i += THREADS) {
      unsigned long long rec = tmp[base + i];
      int ld = (int)((rec >> 32) & 63);
      int rk = atomicAdd(&h2[ld], 1);
      ed[base + exc[ld] + rk] = (unsigned)((rec >> 16) & 0xFFFF) | ((unsigned)(rec & 0xFFFF) << 16);
    }
    __syncthreads();
    if (tid < 64) {
      int v = b * 64 + tid;
      if (v < N) {
        float s = 0.f;
        for (int j = exc[tid]; j < exc[tid + 1]; ++j) s += bf2f((unsigned short)(ed[base + j] >> 16));
        float d = rsqrtf(1.0f + s);
        dis[v] = d;
        rp[v] = base + exc[tid];
        for (int j = exc[tid]; j < exc[tid + 1]; ++j) {
          unsigned rec = ed[base + j];
          ed[base + j] = (rec & 0xFFFF) |
                         ((unsigned)f2bf(bf2f((unsigned short)(rec >> 16)) * d) << 16);
        }
      }
    }
  }
  if (b == 0 && tid == 0) rp[N] = E;
}

// ---------- one-time weight prep: f32 [k][n] -> bf16 transposed [n][k], XOR-swizzled ----------
__global__ void k_prew(const float* __restrict__ W_s, const float* __restrict__ W_f,
                       unsigned* __restrict__ Wsw) {
  int m = blockIdx.x;                 // 0..2L-1: matrix id (l = m>>1, branch = m&1)
  const float* W = ((m & 1) ? W_f : W_s) + (size_t)(m >> 1) * 128 * 128;
  unsigned* dst = Wsw + (size_t)m * 8192;
  int tid = threadIdx.x;
  #pragma unroll
  for (int p = 0; p < 32; ++p) {
    int idx = p * 256 + tid;          // dword index
    int kp = idx & 63, n = idx >> 6;  // k = 2*kp
    float w0 = W[(2 * kp) * 128 + n];
    float w1 = W[(2 * kp + 1) * 128 + n];
    unsigned pk = (unsigned)f2bf(w0) | ((unsigned)f2bf(w1) << 16);
    unsigned byte = (unsigned)(n * 256 + kp * 4) ^ ((unsigned)(n & 7) << 4);
    *(unsigned*)((char*)dst + byte) = pk;
  }
}

// ---------- MFMA GEMM with fused BN+ReLU+cast on the A path ----------
// mode 0: A = x (f32), pack to bf16. mode 1: A = agg (bf16); apply per-col
// scale/shift (stats,gamma,beta of the PREVIOUS layer) + ReLU, repack.
// C(bf16) = dis[row] * (A' @ W).
__global__ __launch_bounds__(THREADS) void k_gemm_mfma(
    const void* __restrict__ Araw,
    const unsigned* __restrict__ Wsw,
    const float* __restrict__ dis_s, const float* __restrict__ dis_f,
    const double* __restrict__ stats, const float* __restrict__ gamma,
    const float* __restrict__ beta,
    unsigned short* __restrict__ C0, unsigned short* __restrict__ C1,
    int N, int mode) {
  const unsigned* Wm  = Wsw + (size_t)blockIdx.y * 8192;
  const float*    dis = blockIdx.y ? dis_f : dis_s;
  unsigned short* C   = blockIdx.y ? C1 : C0;
  const float*          Af = (const float*)Araw;
  const unsigned short* Ab = (const unsigned short*)Araw;
  __shared__ unsigned Wt[8192];                  // 32 KiB
  __shared__ float scl[128], shf[128];
  int tid = threadIdx.x;
  #pragma unroll
  for (int i = 0; i < 8; ++i)
    ((float4*)Wt)[i * 256 + tid] = ((const float4*)Wm)[i * 256 + tid];
  if (mode && tid < 128) {
    double invN = 1.0 / (double)N;
    double m   = stats[tid] * invN;
    double var = stats[128 + tid] * invN - m * m;
    float s = gamma[tid] * rsqrtf((float)var + 1e-5f);
    scl[tid] = s;
    shf[tid] = beta[tid] - (float)m * s;
  }
  __syncthreads();

  int wid = tid >> 6, lane = tid & 63;
  int kg = lane >> 4;                            // 0..3
  int rbase = blockIdx.x * 128 + wid * 32;
  int rown[2];
  #pragma unroll
  for (int rt = 0; rt < 2; ++rt) {
    int r = rbase + rt * 16 + (lane & 15); if (r > N - 1) r = N - 1;   // clamp; store guarded
    rown[rt] = r;
  }

  f32x4 acc[2][8];
  #pragma unroll
  for (int rt = 0; rt < 2; ++rt)
    #pragma unroll
    for (int nt = 0; nt < 8; ++nt) acc[rt][nt] = (f32x4){0.f, 0.f, 0.f, 0.f};

  #pragma unroll
  for (int ks = 0; ks < 4; ++ks) {
    int kbase = ks * 32 + kg * 8;
    s16x8 af[2];
    #pragma unroll
    for (int rt = 0; rt < 2; ++rt) {
      float a[8];
      if (mode) {
        s16x8 raw = *(const s16x8*)(Ab + (size_t)rown[rt] * 128 + kbase);
        #pragma unroll
        for (int j = 0; j < 8; ++j) {
          float vv = bf2f((unsigned short)raw[j]);
          vv = fmaf(vv, scl[kbase + j], shf[kbase + j]);
          a[j] = vv > 0.f ? vv : 0.f;
        }
      } else {
        float4 a0 = *(const float4*)(Af + (size_t)rown[rt] * 128 + kbase);
        float4 a1 = *(const float4*)(Af + (size_t)rown[rt] * 128 + kbase + 4);
        a[0] = a0.x; a[1] = a0.y; a[2] = a0.z; a[3] = a0.w;
        a[4] = a1.x; a[5] = a1.y; a[6] = a1.z; a[7] = a1.w;
      }
      s16x8 f;
      #pragma unroll
      for (int j = 0; j < 8; ++j) f[j] = (short)f2bf(a[j]);
      af[rt] = f;
    }
    #pragma unroll
    for (int nt = 0; nt < 8; ++nt) {
      int col = nt * 16 + (lane & 15);
      unsigned byte = (unsigned)(col * 256 + kbase * 2) ^ ((unsigned)(col & 7) << 4);
      s16x8 bfrag = *(const s16x8*)((char*)Wt + byte);
      acc[0][nt] = __builtin_amdgcn_mfma_f32_16x16x32_bf16(af[0], bfrag, acc[0][nt], 0, 0, 0);
      acc[1][nt] = __builtin_amdgcn_mfma_f32_16x16x32_bf16(af[1], bfrag, acc[1][nt], 0, 0, 0);
    }
  }
  // C/D layout (m89): col = lane&15, row = (lane>>4)*4 + reg. Scale row by dis[row].
  #pragma unroll
  for (int rt = 0; rt < 2; ++rt) {
    #pragma unroll
    for (int r = 0; r < 4; ++r) {
      int row = rbase + rt * 16 + kg * 4 + r;
      if (row < N) {
        float d = dis[row];
        #pragma unroll
        for (int nt = 0; nt < 8; ++nt) {
          int col = nt * 16 + (lane & 15);
          C[(size_t)row * 128 + col] = f2bf(acc[rt][nt][r] * d);
        }
      }
    }
  }
}

// ---------- aggregation (separated loops, dis-folded weights) + fused BN stats ----------
// agg(bf16)[v] = dvs*t's[v] + dvf*t'f[v] + Σ_s w''·t's[src] + Σ_f w''·t'f[src]
__global__ __launch_bounds__(THREADS) void k_gather(
    const unsigned short* __restrict__ t_sc, const unsigned short* __restrict__ t_fc,
    const int* __restrict__ rp_s, const unsigned* __restrict__ ed_s,
    const int* __restrict__ rp_f, const unsigned* __restrict__ ed_f,
    const float* __restrict__ dis_s, const float* __restrict__ dis_f,
    unsigned short* __restrict__ aggb, float* __restrict__ pb, int N) {
  __shared__ float redS[4][128], redQ[4][128];
  int tid    = threadIdx.x;
  int wid    = tid >> 6;
  int lane   = tid & 63;
  int gw     = (blockIdx.x * blockDim.x + tid) >> 6;
  int nwaves = (gridDim.x * blockDim.x) >> 6;
  float s0 = 0.f, s1 = 0.f, q0 = 0.f, q1 = 0.f;
  for (int v = gw; v < N; v += nwaves) {
    float dvs = dis_s[v], dvf = dis_f[v];
    unsigned a = ((const unsigned*)(t_sc + (size_t)v * 128))[lane];
    unsigned b = ((const unsigned*)(t_fc + (size_t)v * 128))[lane];
    float ax = bf2f((unsigned short)a) * dvs + bf2f((unsigned short)b) * dvf;
    float ay = bf2f((unsigned short)(a >> 16)) * dvs + bf2f((unsigned short)(b >> 16)) * dvf;

    #pragma unroll 1
    for (int g = 0; g < 2; ++g) {
      const int*            rp = g ? rp_f : rp_s;
      const unsigned*       ed = g ? ed_f : ed_s;
      const unsigned short* t  = g ? t_fc : t_sc;
      int e0 = rp[v], e1 = rp[v + 1];
      int e = e0;
      for (; e + 7 < e1; e += 8) {          // 8 independent row loads in flight
        unsigned q[8];
        #pragma unroll
        for (int j = 0; j < 8; ++j) q[j] = ed[e + j];
        unsigned r[8];
        #pragma unroll
        for (int j = 0; j < 8; ++j)
          r[j] = ((const unsigned*)(t + (size_t)(q[j] & 0xFFFF) * 128))[lane];
        #pragma unroll
        for (int j = 0; j < 8; ++j) {
          float w = bf2f((unsigned short)(q[j] >> 16));
          ax = fmaf(bf2f((unsigned short)r[j]), w, ax);
          ay = fmaf(bf2f((unsigned short)(r[j] >> 16)), w, ay);
        }
      }
      for (; e + 1 < e1; e += 2) {
        unsigned qa = ed[e], qb = ed[e + 1];
        unsigned ra = ((const unsigned*)(t + (size_t)(qa & 0xFFFF) * 128))[lane];
        unsigned rb = ((const unsigned*)(t + (size_t)(qb & 0xFFFF) * 128))[lane];
        float wa = bf2f((unsigned short)(qa >> 16)), wb = bf2f((unsigned short)(qb >> 16));
        ax = fmaf(bf2f((unsigned short)ra), wa, ax); ay = fmaf(bf2f((unsigned short)(ra >> 16)), wa, ay);
        ax = fmaf(bf2f((unsigned short)rb), wb, ax); ay = fmaf(bf2f((unsigned short)(rb >> 16)), wb, ay);
      }
      if (e < e1) {
        unsigned qa = ed[e];
        unsigned ra = ((const unsigned*)(t + (size_t)(qa & 0xFFFF) * 128))[lane];
        float wa = bf2f((unsigned short)(qa >> 16));
        ax = fmaf(bf2f((unsigned short)ra), wa, ax);
        ay = fmaf(bf2f((unsigned short)(ra >> 16)), wa, ay);
      }
    }
    ((unsigned*)(aggb + (size_t)v * 128))[lane] =
        (unsigned)f2bf(ax) | ((unsigned)f2bf(ay) << 16);
    s0 += ax; s1 += ay;
    q0 = fmaf(ax, ax, q0); q1 = fmaf(ay, ay, q1);
  }
  // block-level stats partials (deterministic; no atomics)
  redS[wid][lane * 2] = s0; redS[wid][lane * 2 + 1] = s1;
  redQ[wid][lane * 2] = q0; redQ[wid][lane * 2 + 1] = q1;
  __syncthreads();
  if (tid < 128) {
    pb[(size_t)blockIdx.x * 256 + tid] =
        redS[0][tid] + redS[1][tid] + redS[2][tid] + redS[3][tid];
  } else {
    int c = tid - 128;
    pb[(size_t)blockIdx.x * 256 + tid] =
        redQ[0][c] + redQ[1][c] + redQ[2][c] + redQ[3][c];
  }
}

// ---------- hierarchical deterministic stats reduce: NG x 256 -> 64 x 256 -> 256 ----------
__global__ void k_stats2a(const float* __restrict__ pb, double* __restrict__ pb2) {
  int b = blockIdx.x, t = threadIdx.x;
  double s = 0;
  for (int r = 0; r < NG / 64; ++r)
    s += (double)pb[(size_t)(b * (NG / 64) + r) * 256 + t];
  pb2[(size_t)b * 256 + t] = s;
}

__global__ void k_stats2b(const double* __restrict__ pb2, double* __restrict__ stats) {
  int t = threadIdx.x;
  double s = 0;
  for (int b = 0; b < 64; ++b) s += pb2[(size_t)b * 256 + t];
  stats[t] = s;
}

// ---------- final-layer BN+ReLU: agg bf16 -> f32 out ----------
__global__ void k_bn(const unsigned short* __restrict__ aggb, const double* __restrict__ stats,
                     const float* __restrict__ gamma, const float* __restrict__ beta,
                     float* __restrict__ outf, int N) {
  int total2 = N * 64;   // dwords (2 cols each)
  double invN = 1.0 / (double)N;
  for (int i = blockIdx.x * blockDim.x + threadIdx.x; i < total2; i += gridDim.x * blockDim.x) {
    int c = (i & 63) * 2;
    unsigned pk = ((const unsigned*)aggb)[i];
    double m0   = stats[c] * invN;
    double var0 = stats[128 + c] * invN - m0 * m0;
    float sc0 = gamma[c] * rsqrtf((float)var0 + 1e-5f);
    float sh0 = beta[c] - (float)m0 * sc0;
    double m1   = stats[c + 1] * invN;
    double var1 = stats[128 + c + 1] * invN - m1 * m1;
    float sc1 = gamma[c + 1] * rsqrtf((float)var1 + 1e-5f);
    float sh1 = beta[c + 1] - (float)m1 * sc1;
    float v0 = fmaf(bf2f((unsigned short)pk), sc0, sh0);
    float v1 = fmaf(bf2f((unsigned short)(pk >> 16)), sc1, sh1);
    ((float2*)outf)[i] = make_float2(v0 > 0.f ? v0 : 0.f, v1 > 0.f ? v1 : 0.f);
  }
}

extern "C" void kernel_launch(void* const* d_in, const int* in_sizes, int n_in,
                              void* d_out, int out_size, void* d_ws, size_t ws_size,
                              hipStream_t stream) {
  const float* x     = (const float*)d_in[0];
  const int*   ei_s  = (const int*)d_in[1];
  const float* w_s   = (const float*)d_in[2];
  const int*   ei_f  = (const int*)d_in[3];
  const float* w_f   = (const float*)d_in[4];
  const float* W_s   = (const float*)d_in[5];
  const float* W_f   = (const float*)d_in[7];
  const float* gamma = (const float*)d_in[9];
  const float* beta  = (const float*)d_in[10];
  float* out = (float*)d_out;

  const int N = in_sizes[0] / 128;
  const int E = in_sizes[2];
  const int L = in_sizes[5] / (128 * 128);
  const int nbk = (N + 63) >> 6;            // 782 coarse buckets (64 vertices each)
  const int M = nbk * NBLKA;                // count-matrix size per graph

  char* ws = (char*)d_ws;
  size_t off = 0;
  auto alloc = [&](size_t bytes) -> void* {
    void* p = (void*)(ws + off);
    off += (bytes + 255) & ~(size_t)255;
    return p;
  };
  double* stats = (double*)alloc(256 * sizeof(double));
  float*  pb    = (float*)alloc((size_t)NG * 256 * sizeof(float));
  double* pb2   = (double*)alloc((size_t)64 * 256 * sizeof(double));
  unsigned* Wsw = (unsigned*)alloc((size_t)2 * L * 8192 * 4);
  unsigned short* t_sc = (unsigned short*)alloc((size_t)N * 128 * 2);
  unsigned short* t_fc = (unsigned short*)alloc((size_t)N * 128 * 2);
  unsigned short* aggb = (unsigned short*)alloc((size_t)N * 128 * 2);
  float* dis_s = (float*)alloc((size_t)N * 4);
  float* dis_f = (float*)alloc((size_t)N * 4);
  int*   rp_s  = (int*)alloc((size_t)(N + 1) * 4);
  int*   rp_f  = (int*)alloc((size_t)(N + 1) * 4);
  int*   hm_s  = (int*)alloc((size_t)M * 4);
  int*   hm_f  = (int*)alloc((size_t)M * 4);
  int*   sc_s  = (int*)alloc((size_t)M * 4);
  int*   sc_f  = (int*)alloc((size_t)M * 4);
  unsigned long long* tmp_s = (unsigned long long*)alloc((size_t)E * 8);
  unsigned long long* tmp_f = (unsigned long long*)alloc((size_t)E * 8);
  unsigned* ed_s = (unsigned*)alloc((size_t)E * 4);
  unsigned* ed_f = (unsigned*)alloc((size_t)E * 4);
  int* bsum = (int*)alloc((size_t)2 * nbk * 4);

  dim3 ga(NBLKA, 2), gm(nbk, 2);

  // one-time weight prep + CSR/degree build (layer-invariant)
  k_prew<<<2 * L, THREADS, 0, stream>>>(W_s, W_f, Wsw);
  k_histA<<<ga, THREADS, 0, stream>>>(ei_s + E, ei_f + E, hm_s, hm_f, E, nbk);
  k_scanA1<<<gm, THREADS, 0, stream>>>(hm_s, hm_f, sc_s, sc_f, bsum, M, nbk);
  k_scanA2<<<2, THREADS, 0, stream>>>(bsum, nbk);
  k_scatA<<<ga, THREADS, 0, stream>>>(ei_s, w_s, ei_f, w_f, sc_s, sc_f, bsum,
                                      tmp_s, tmp_f, E, nbk);
  k_passB<<<gm, THREADS, 0, stream>>>(tmp_s, tmp_f, sc_s, sc_f, bsum, ed_s, ed_f,
                                      rp_s, rp_f, dis_s, dis_f, E, N, nbk);

  for (int l = 0; l < L; ++l) {
    dim3 gg((N + 127) / 128, 2);
    const void* Ain = (l == 0) ? (const void*)x : (const void*)aggb;
    const float* gm_prev = l ? gamma + (size_t)(l - 1) * 128 : gamma;
    const float* bt_prev = l ? beta  + (size_t)(l - 1) * 128 : beta;
    k_gemm_mfma<<<gg, THREADS, 0, stream>>>(Ain, Wsw + (size_t)l * 2 * 8192,
                                            dis_s, dis_f, stats, gm_prev, bt_prev,
                                            t_sc, t_fc, N, l ? 1 : 0);
    k_gather<<<NG, THREADS, 0, stream>>>(t_sc, t_fc, rp_s, ed_s, rp_f, ed_f,
                                         dis_s, dis_f, aggb, pb, N);
    k_stats2a<<<64, 256, 0, stream>>>(pb, pb2);
    k_stats2b<<<1, 256, 0, stream>>>(pb2, stats);
  }
  k_bn<<<2048, THREADS, 0, stream>>>(aggb, stats, gamma + (size_t)(L - 1) * 128,
                                     beta + (size_t)(L - 1) * 128, out, N);
}